// Round 14
// baseline (214.724 us; speedup 1.0000x reference)
//
#include <hip/hip_runtime.h>
#include <math.h>

// Problem constants
#define NB 4
#define HB 256
#define WB 256
#define CB 8
#define NPIX (NB*HB*WB)   // 262144
#define W2B 129           // rfft bins along W
#define TWO_PI_F 6.283185307179586f

typedef float f32x4 __attribute__((ext_vector_type(4)));

__device__ __forceinline__ float gelu_f(float x){
    float z = 0.7978845608028654f*(x + 0.044715f*x*x*x);
    return x * __builtin_amdgcn_rcpf(1.0f + __expf(-2.0f*z));
}

__device__ __forceinline__ unsigned pack_bf16x2(float a, float b){
    unsigned ua = __float_as_uint(a), ub = __float_as_uint(b);
    ua = (ua + 0x7FFFu + ((ua >> 16) & 1u)) >> 16;
    ub = (ub + 0x7FFFu + ((ub >> 16) & 1u)) >> 16;
    return ua | (ub << 16);
}
__device__ __forceinline__ float2 unpack_bf16x2(unsigned v){
    return make_float2(__uint_as_float(v << 16), __uint_as_float(v & 0xFFFF0000u));
}

__device__ __forceinline__ void ldcp(float* dst, const float* __restrict__ src, int n, int t){
    for (int i = t; i < n; i += 256) dst[i] = src[i];
}

// ---- prep (unchanged, round-10/13 version) -----------------------------
// Grid: [0..128] spectral filter; [129..640] gamma 2px/thr; [641..1152] delta.
// mat layout (uint4 rows): mat[(pix>>6)*2048 + j*256 + (pix&63)*4 + c]
// fpack layout: fpack[w2*16384 + q*1024 + h*4 + c] = bf16x2{re,im}
__global__ __launch_bounds__(256) void prep_kernel(
    const float* __restrict__ kin,
    const float* gw1,const float* gb1,const float* gw2,const float* gb2,const float* gw3,const float* gb3,
    const float* dw1,const float* db1,const float* dw2,const float* db2,const float* dw3,const float* db3,
    const float* fw1,const float* fb1,const float* fw2,const float* fb2,const float* fw3,const float* fb3,
    const float* iw1,const float* ib1,const float* iw2,const float* ib2,const float* iw3,const float* ib3,
    unsigned* __restrict__ gmat, unsigned* __restrict__ dmat,
    unsigned* __restrict__ fpack)
{
    __shared__ __align__(16) float sw[2816];
    int t = threadIdx.x;
    int b = blockIdx.x;
    if (b >= 129){
        int gd = (b >= 641);
        const float* w1 = gd ? dw1 : gw1;  const float* b1 = gd ? db1 : gb1;
        const float* w2 = gd ? dw2 : gw2;  const float* b2 = gd ? db2 : gb2;
        const float* w3 = gd ? dw3 : gw3;  const float* b3 = gd ? db3 : gb3;
        ldcp(sw+0,   w1,  32, t); ldcp(sw+32,  b1, 16, t);
        ldcp(sw+48,  w2, 256, t); ldcp(sw+304, b2, 16, t);
        ldcp(sw+320, w3,1024, t); ldcp(sw+1344,b3, 64, t);
        __syncthreads();
        unsigned* mat = gd ? dmat : gmat;
        int p0 = (b - (gd ? 641 : 129))*512 + t;
        int p1 = p0 + 256;
        float2 kv0 = ((const float2*)kin)[p0];
        float2 kv1 = ((const float2*)kin)[p1];
        size_t base0 = (size_t)(p0 >> 6)*2048 + (size_t)(p0 & 63)*4;
        size_t base1 = (size_t)(p1 >> 6)*2048 + (size_t)(p1 & 63)*4;
        float h1[2][16], h2[2][16];
#pragma unroll
        for (int o = 0; o < 16; ++o){
            float wx = sw[o], wy = sw[16+o], bo = sw[32+o];
            h1[0][o] = gelu_f(kv0.x*wx + kv0.y*wy + bo);
            h1[1][o] = gelu_f(kv1.x*wx + kv1.y*wy + bo);
        }
#pragma unroll
        for (int oc = 0; oc < 4; ++oc){
            f32x4 bb = *(const f32x4*)(sw + 304 + oc*4);
            f32x4 a0 = bb, a1 = bb;
#pragma unroll
            for (int i = 0; i < 16; ++i){
                f32x4 w = *(const f32x4*)(sw + 48 + i*16 + oc*4);
                a0 += h1[0][i]*w; a1 += h1[1][i]*w;
            }
            h2[0][oc*4+0]=gelu_f(a0.x); h2[0][oc*4+1]=gelu_f(a0.y);
            h2[0][oc*4+2]=gelu_f(a0.z); h2[0][oc*4+3]=gelu_f(a0.w);
            h2[1][oc*4+0]=gelu_f(a1.x); h2[1][oc*4+1]=gelu_f(a1.y);
            h2[1][oc*4+2]=gelu_f(a1.z); h2[1][oc*4+3]=gelu_f(a1.w);
        }
        const float s = 1.0f/64.0f;
#pragma unroll
        for (int j = 0; j < 8; ++j){
            f32x4 bA = *(const f32x4*)(sw + 1344 + j*8);
            f32x4 bB = *(const f32x4*)(sw + 1344 + j*8 + 4);
            f32x4 A0 = bA, A1 = bB, B0 = bA, B1 = bB;
#pragma unroll
            for (int i = 0; i < 16; ++i){
                f32x4 wA = *(const f32x4*)(sw + 320 + i*64 + j*8);
                f32x4 wB = *(const f32x4*)(sw + 320 + i*64 + j*8 + 4);
                float h0 = h2[0][i], h1v = h2[1][i];
                A0 += h0*wA; A1 += h0*wB;
                B0 += h1v*wA; B1 += h1v*wB;
            }
            uint4 o0 = { pack_bf16x2(A0.x*s,A0.y*s), pack_bf16x2(A0.z*s,A0.w*s),
                         pack_bf16x2(A1.x*s,A1.y*s), pack_bf16x2(A1.z*s,A1.w*s) };
            uint4 o1 = { pack_bf16x2(B0.x*s,B0.y*s), pack_bf16x2(B0.z*s,B0.w*s),
                         pack_bf16x2(B1.x*s,B1.y*s), pack_bf16x2(B1.z*s,B1.w*s) };
            *(uint4*)(mat + base0 + (size_t)j*256) = o0;
            *(uint4*)(mat + base1 + (size_t)j*256) = o1;
        }
    } else {
        ldcp(sw+0,   fw1,  32, t); ldcp(sw+32,  fb1, 16, t);
        ldcp(sw+48,  fw2, 256, t); ldcp(sw+304, fb2, 16, t);
        ldcp(sw+320, fw3,1024, t); ldcp(sw+1344,fb3, 64, t);
        ldcp(sw+1408+0,   iw1,  32, t); ldcp(sw+1408+32,  ib1, 16, t);
        ldcp(sw+1408+48,  iw2, 256, t); ldcp(sw+1408+304, ib2, 16, t);
        ldcp(sw+1408+320, iw3,1024, t); ldcp(sw+1408+1344,ib3, 64, t);
        __syncthreads();
        int w2 = b;                                 // 0..128 (kx)
        float x = (float)w2;
        float y = (float)(t < 128 ? t : t - 256);   // ky signed, t = h-freq
        float h1r[16], h1i[16], h2r[16], h2i[16];
#pragma unroll
        for (int o = 0; o < 16; ++o){
            h1r[o] = gelu_f(x*sw[o] + y*sw[16+o] + sw[32+o]);
            h1i[o] = gelu_f(x*sw[1408+o] + y*sw[1408+16+o] + sw[1408+32+o]);
        }
#pragma unroll
        for (int o = 0; o < 16; ++o){
            float ar = sw[304+o], ai = sw[1408+304+o];
#pragma unroll
            for (int i = 0; i < 16; ++i){
                ar += h1r[i]*sw[48+i*16+o];
                ai += h1i[i]*sw[1408+48+i*16+o];
            }
            h2r[o] = gelu_f(ar); h2i[o] = gelu_f(ai);
        }
        const float s = 1.0f/64.0f;
#pragma unroll
        for (int q = 0; q < 16; ++q){
            f32x4 aR = *(const f32x4*)(sw + 1344 + q*4);
            f32x4 aI = *(const f32x4*)(sw + 1408 + 1344 + q*4);
#pragma unroll
            for (int i = 0; i < 16; ++i){
                aR += h2r[i] * *(const f32x4*)(sw + 320 + i*64 + q*4);
                aI += h2i[i] * *(const f32x4*)(sw + 1408 + 320 + i*64 + q*4);
            }
            uint4 out = { pack_bf16x2(aR.x*s, aI.x*s), pack_bf16x2(aR.y*s, aI.y*s),
                          pack_bf16x2(aR.z*s, aI.z*s), pack_bf16x2(aR.w*s, aI.w*s) };
            *(uint4*)(fpack + (size_t)w2*16384 + (size_t)q*1024 + (size_t)t*4) = out;
        }
    }
}

// ---- 8-channel (2x f32x4) 256-pt FFT core: one barrier set, regs out ----
__device__ __forceinline__ void fft256v8_core(
    f32x4 (*xr)[256], f32x4 (*xi)[256], int t, float sgn,
    f32x4& o0R, f32x4& o0I, f32x4& o1R, f32x4& o1I)
{
    int n2 = t >> 4, k1 = t & 15;
    float csA, snA; __sincosf(sgn*TWO_PI_F*(float)k1*(1.0f/16.0f), &snA, &csA);
    f32x4 a0r={0.f,0.f,0.f,0.f}, a0i=a0r, a1r=a0r, a1i=a0r;
    float cw = 1.f, sw = 0.f;
#pragma unroll
    for (int n1 = 0; n1 < 16; ++n1){
        int idx = 16*n1 + n2;
        f32x4 v0r = xr[0][idx], v0i = xi[0][idx];
        f32x4 v1r = xr[1][idx], v1i = xi[1][idx];
        a0r += v0r*cw - v0i*sw;  a0i += v0r*sw + v0i*cw;
        a1r += v1r*cw - v1i*sw;  a1i += v1r*sw + v1i*cw;
        float cn = cw*csA - sw*snA;
        sw = cw*snA + sw*csA; cw = cn;
    }
    float cs2, sn2; __sincosf(sgn*TWO_PI_F*(float)(n2*k1)*(1.0f/256.0f), &sn2, &cs2);
    f32x4 b0r = a0r*cs2 - a0i*sn2, b0i = a0r*sn2 + a0i*cs2;
    f32x4 b1r = a1r*cs2 - a1i*sn2, b1i = a1r*sn2 + a1i*cs2;
    __syncthreads();
    xr[0][t]=b0r; xi[0][t]=b0i; xr[1][t]=b1r; xi[1][t]=b1i;
    __syncthreads();
    int k1b = t & 15, k2 = t >> 4;
    float csB, snB; __sincosf(sgn*TWO_PI_F*(float)k2*(1.0f/16.0f), &snB, &csB);
    f32x4 y0r={0.f,0.f,0.f,0.f}, y0i=y0r, y1r=y0r, y1i=y0r;
    cw = 1.f; sw = 0.f;
#pragma unroll
    for (int n2b = 0; n2b < 16; ++n2b){
        int idx = n2b*16 + k1b;
        f32x4 c0r = xr[0][idx], c0i = xi[0][idx];
        f32x4 c1r = xr[1][idx], c1i = xi[1][idx];
        y0r += c0r*cw - c0i*sw;  y0i += c0r*sw + c0i*cw;
        y1r += c1r*cw - c1i*sw;  y1i += c1r*sw + c1i*cw;
        float cn = cw*csB - sw*snB;
        sw = cw*snB + sw*csB; cw = cn;
    }
    o0R = y0r; o0I = y0i; o1R = y1r; o1I = y1i;
}

// fwd for a ROW PAIR: dv0/dv1 rows h0,h0+1 -> FFT -> Hermitian -> spec.
// Entry condition: safe to write XR/XI (caller synced).
__device__ __forceinline__ void fwd_store2(
    f32x4 (*XR)[256], f32x4 (*XI)[256], const float* dv0, const float* dv1,
    int t, int n, int h0, float2* __restrict__ spec)
{
    XR[0][t] = (f32x4){dv0[0],dv0[2],dv0[4],dv0[6]};
    XI[0][t] = (f32x4){dv0[1],dv0[3],dv0[5],dv0[7]};
    XR[1][t] = (f32x4){dv1[0],dv1[2],dv1[4],dv1[6]};
    XI[1][t] = (f32x4){dv1[1],dv1[3],dv1[5],dv1[7]};
    __syncthreads();
    f32x4 y0R, y0I, y1R, y1I;
    fft256v8_core(XR, XI, t, -1.f, y0R, y0I, y1R, y1I);
    __syncthreads();            // stage-2 reads done everywhere
    XR[0][t]=y0R; XI[0][t]=y0I; XR[1][t]=y1R; XI[1][t]=y1I;
    __syncthreads();            // mirror values ready
    if (t <= 128){
        int m = (256 - t) & 255;
#pragma unroll
        for (int r = 0; r < 2; ++r){
            f32x4 zr = XR[r][t], zi = XI[r][t], yr = XR[r][m], yi = XI[r][m];
            float4* dst = (float4*)(spec + (((size_t)n*129 + t)*256 + (h0+r))*8);
            dst[0] = make_float4(0.5f*(zr.x+yr.x), 0.5f*(zi.x-yi.x), 0.5f*(zi.x+yi.x), 0.5f*(yr.x-zr.x));
            dst[1] = make_float4(0.5f*(zr.y+yr.y), 0.5f*(zi.y-yi.y), 0.5f*(zi.y+yi.y), 0.5f*(yr.y-zr.y));
            dst[2] = make_float4(0.5f*(zr.z+yr.z), 0.5f*(zi.z-yi.z), 0.5f*(zi.z+yi.z), 0.5f*(yr.z-zr.z));
            dst[3] = make_float4(0.5f*(zr.w+yr.w), 0.5f*(zi.w-yi.w), 0.5f*(zi.w+yi.w), 0.5f*(yr.w-zr.w));
        }
    }
}

__device__ __forceinline__ void herm_pack(
    const float4& q0, const float4& q1, const float4& q2, const float4& q3,
    int t, f32x4& xr, f32x4& xi)
{
    if (t <= 128){
        xr = (f32x4){q0.x - q0.w, q1.x - q1.w, q2.x - q2.w, q3.x - q3.w};
        xi = (f32x4){q0.y + q0.z, q1.y + q1.z, q2.y + q2.z, q3.y + q3.z};
    } else {
        xr = (f32x4){ q0.x + q0.w,  q1.x + q1.w,  q2.x + q2.w,  q3.x + q3.w};
        xi = (f32x4){-q0.y + q0.z, -q1.y + q1.z, -q2.y + q2.z, -q3.y + q3.z};
    }
}

// inverse for a ROW PAIR -> gu0[8], gu1[8] in registers
__device__ __forceinline__ void inv_fft_to_gu2(
    const float2* __restrict__ spec, f32x4 (*XR)[256], f32x4 (*XI)[256],
    int t, int n, int h0, float* gu0, float* gu1)
{
    int w2 = (t <= 128) ? t : 256 - t;
    const float4* rp0 = (const float4*)(spec + (((size_t)n*129 + w2)*256 + h0)*8);
    const float4* rp1 = (const float4*)(spec + (((size_t)n*129 + w2)*256 + h0+1)*8);
    float4 a0=rp0[0], a1=rp0[1], a2=rp0[2], a3=rp0[3];
    float4 b0=rp1[0], b1=rp1[1], b2=rp1[2], b3=rp1[3];
    f32x4 xr, xi;
    herm_pack(a0,a1,a2,a3, t, xr, xi);  XR[0][t]=xr; XI[0][t]=xi;
    herm_pack(b0,b1,b2,b3, t, xr, xi);  XR[1][t]=xr; XI[1][t]=xi;
    __syncthreads();
    f32x4 g0r,g0i,g1r,g1i;
    fft256v8_core(XR, XI, t, +1.f, g0r,g0i,g1r,g1i);
    const float s = 1.0f/65536.0f;
    gu0[0]=g0r.x*s; gu0[1]=g0i.x*s; gu0[2]=g0r.y*s; gu0[3]=g0i.y*s;
    gu0[4]=g0r.z*s; gu0[5]=g0i.z*s; gu0[6]=g0r.w*s; gu0[7]=g0i.w*s;
    gu1[0]=g1r.x*s; gu1[1]=g1i.x*s; gu1[2]=g1r.y*s; gu1[3]=g1i.y*s;
    gu1[4]=g1r.z*s; gu1[5]=g1i.z*s; gu1[6]=g1r.w*s; gu1[7]=g1i.w*s;
}

// matvec accumulate: acc[k] += v[j] * M[j][k], M in uint4-row layout
__device__ __forceinline__ void matvec_acc(const unsigned* __restrict__ mat,
                                           size_t base, const float* v, float* acc)
{
    const uint4* mp = (const uint4*)(mat + base);
#pragma unroll
    for (int j = 0; j < 8; ++j){
        uint4 q = mp[j*64];
        float vj = v[j];
        float2 f0 = unpack_bf16x2(q.x), f1 = unpack_bf16x2(q.y);
        float2 f2 = unpack_bf16x2(q.z), f3 = unpack_bf16x2(q.w);
        acc[0] += vj*f0.x; acc[1] += vj*f0.y;
        acc[2] += vj*f1.x; acc[3] += vj*f1.y;
        acc[4] += vj*f2.x; acc[5] += vj*f2.y;
        acc[6] += vj*f3.x; acc[7] += vj*f3.y;
    }
}

__device__ __forceinline__ void load8(const float* p, float* v){
    float4 a = ((const float4*)p)[0], b = ((const float4*)p)[1];
    v[0]=a.x; v[1]=a.y; v[2]=a.z; v[3]=a.w; v[4]=b.x; v[5]=b.y; v[6]=b.z; v[7]=b.w;
}
__device__ __forceinline__ void store8(float* p, const float* v){
    ((float4*)p)[0] = make_float4(v[0],v[1],v[2],v[3]);
    ((float4*)p)[1] = make_float4(v[4],v[5],v[6],v[7]);
}

// ---- initial: du = u*Delta for row pair, forward rfft ------------------
__global__ __launch_bounds__(256) void fft_fwd_kernel(
    const float* __restrict__ u, const unsigned* __restrict__ dmat,
    float2* __restrict__ spec)
{
    __shared__ f32x4 XR[2][256], XI[2][256];
    int t = threadIdx.x, bid = blockIdx.x;
    int n = bid >> 7, h0 = (bid & 127)*2;
    float uv0[8], uv1[8], dv0[8]={0,0,0,0,0,0,0,0}, dv1[8]={0,0,0,0,0,0,0,0};
    size_t row0 = (size_t)(n*256 + h0);
    load8(u + row0*2048 + (size_t)t*8, uv0);
    load8(u + (row0+1)*2048 + (size_t)t*8, uv1);
    size_t base0 = (row0*4 + (t>>6))*2048 + (size_t)(t&63)*4;
    size_t base1 = ((row0+1)*4 + (t>>6))*2048 + (size_t)(t&63)*4;
    matvec_acc(dmat, base0, uv0, dv0);
    matvec_acc(dmat, base1, uv1, dv1);
    fwd_store2(XR, XI, dv0, dv1, t, n, h0, spec);
}

// ---- fused: cfft along H -> per-frequency 8x8 complex mat -> icfft -----
// (unchanged from round 13: 256 threads, 8 channels/thread)
__global__ __launch_bounds__(256) void ffth_mult_kernel(
    float2* __restrict__ spec, const unsigned* __restrict__ fpack)
{
    __shared__ f32x4 XR[2][256], XI[2][256];
    int t = threadIdx.x;
    int n = blockIdx.x / 129, w2 = blockIdx.x % 129;
    float2* base = spec + ((size_t)(n*129 + w2))*2048;
    const float4* rp = (const float4*)(base + (size_t)t*8);
    float4 r0 = rp[0], r1 = rp[1], r2 = rp[2], r3 = rp[3];
    XR[0][t] = (f32x4){r0.x, r0.z, r1.x, r1.z};
    XI[0][t] = (f32x4){r0.y, r0.w, r1.y, r1.w};
    XR[1][t] = (f32x4){r2.x, r2.z, r3.x, r3.z};
    XI[1][t] = (f32x4){r2.y, r2.w, r3.y, r3.w};
    __syncthreads();
    f32x4 s0R, s0I, s1R, s1I;
    fft256v8_core(XR, XI, t, -1.f, s0R, s0I, s1R, s1I);

    float sr[8] = {s0R.x,s0R.y,s0R.z,s0R.w, s1R.x,s1R.y,s1R.z,s1R.w};
    float si[8] = {s0I.x,s0I.y,s0I.z,s0I.w, s1I.x,s1I.y,s1I.z,s1I.w};
    f32x4 o0R={0.f,0.f,0.f,0.f}, o0I=o0R, o1R=o0R, o1I=o0R;
    const uint4* fp = (const uint4*)(fpack + (size_t)w2*16384 + (size_t)t*4);
#pragma unroll
    for (int j = 0; j < 8; ++j){
        float sjr = sr[j], sji = si[j];
        uint4 fa = fp[(j*2+0)*256];
        uint4 fb = fp[(j*2+1)*256];
        float2 f0 = unpack_bf16x2(fa.x), f1 = unpack_bf16x2(fa.y);
        float2 f2 = unpack_bf16x2(fa.z), f3 = unpack_bf16x2(fa.w);
        o0R.x += sjr*f0.x - sji*f0.y;  o0I.x += sjr*f0.y + sji*f0.x;
        o0R.y += sjr*f1.x - sji*f1.y;  o0I.y += sjr*f1.y + sji*f1.x;
        o0R.z += sjr*f2.x - sji*f2.y;  o0I.z += sjr*f2.y + sji*f2.x;
        o0R.w += sjr*f3.x - sji*f3.y;  o0I.w += sjr*f3.y + sji*f3.x;
        float2 g0 = unpack_bf16x2(fb.x), g1 = unpack_bf16x2(fb.y);
        float2 g2 = unpack_bf16x2(fb.z), g3 = unpack_bf16x2(fb.w);
        o1R.x += sjr*g0.x - sji*g0.y;  o1I.x += sjr*g0.y + sji*g0.x;
        o1R.y += sjr*g1.x - sji*g1.y;  o1I.y += sjr*g1.y + sji*g1.x;
        o1R.z += sjr*g2.x - sji*g2.y;  o1I.z += sjr*g2.y + sji*g2.x;
        o1R.w += sjr*g3.x - sji*g3.y;  o1I.w += sjr*g3.y + sji*g3.x;
    }
    __syncthreads();
    XR[0][t]=o0R; XI[0][t]=o0I; XR[1][t]=o1R; XI[1][t]=o1I;
    __syncthreads();
    f32x4 v0R, v0I, v1R, v1I;
    fft256v8_core(XR, XI, t, +1.f, v0R, v0I, v1R, v1I);
    float4* wp = (float4*)(base + (size_t)t*8);
    wp[0] = make_float4(v0R.x, v0I.x, v0R.y, v0I.y);
    wp[1] = make_float4(v0R.z, v0I.z, v0R.w, v0I.w);
    wp[2] = make_float4(v1R.x, v1I.x, v1R.y, v1I.y);
    wp[3] = make_float4(v1R.z, v1I.z, v1R.w, v1I.w);
}

// ---- fused step (row pair): inv FFT -> u' -> du -> fwd FFT -------------
__global__ __launch_bounds__(256) void born_step_kernel(
    float2* __restrict__ spec, const float* __restrict__ u_in,
    float* __restrict__ u_out, const unsigned* __restrict__ gmat,
    const unsigned* __restrict__ dmat)
{
    __shared__ f32x4 XR[2][256], XI[2][256];
    int t = threadIdx.x, bid = blockIdx.x;
    int n = bid >> 7, h0 = (bid & 127)*2;
    float gu0[8], gu1[8];
    inv_fft_to_gu2(spec, XR, XI, t, n, h0, gu0, gu1);

    size_t row0 = (size_t)(n*256 + h0);
    float uv0[8], uv1[8];
    load8(u_in + row0*2048 + (size_t)t*8, uv0);
    load8(u_in + (row0+1)*2048 + (size_t)t*8, uv1);
    size_t base0 = (row0*4 + (t>>6))*2048 + (size_t)(t&63)*4;
    size_t base1 = ((row0+1)*4 + (t>>6))*2048 + (size_t)(t&63)*4;

    float e0[8], acc0[8], e1[8], acc1[8];
#pragma unroll
    for (int c = 0; c < 8; ++c){
        e0[c] = gu0[c] - uv0[c]; acc0[c] = 2.0f*uv0[c];
        e1[c] = gu1[c] - uv1[c]; acc1[c] = 2.0f*uv1[c];
    }
    matvec_acc(gmat, base0, e0, acc0);
    matvec_acc(gmat, base1, e1, acc1);
    store8(u_out + row0*2048 + (size_t)t*8, acc0);
    store8(u_out + (row0+1)*2048 + (size_t)t*8, acc1);

    float dv0[8]={0,0,0,0,0,0,0,0}, dv1[8]={0,0,0,0,0,0,0,0};
    matvec_acc(dmat, base0, acc0, dv0);
    matvec_acc(dmat, base1, acc1, dv1);
    __syncthreads();   // guard: laggards may still read XR/XI from inv stage-2
    fwd_store2(XR, XI, dv0, dv1, t, n, h0, spec);
}

// ---- final (row pair): inv FFT -> u' -> gelu(u'+bias) -> out -----------
__global__ __launch_bounds__(256) void final_kernel(
    const float2* __restrict__ spec, const float* __restrict__ u_in,
    const unsigned* __restrict__ gmat, const float* __restrict__ bias,
    float* __restrict__ out)
{
    __shared__ f32x4 XR[2][256], XI[2][256];
    int t = threadIdx.x, bid = blockIdx.x;
    int n = bid >> 7, h0 = (bid & 127)*2;
    float gu0[8], gu1[8];
    inv_fft_to_gu2(spec, XR, XI, t, n, h0, gu0, gu1);

    size_t row0 = (size_t)(n*256 + h0);
    float uv0[8], uv1[8];
    load8(u_in + row0*2048 + (size_t)t*8, uv0);
    load8(u_in + (row0+1)*2048 + (size_t)t*8, uv1);
    size_t base0 = (row0*4 + (t>>6))*2048 + (size_t)(t&63)*4;
    size_t base1 = ((row0+1)*4 + (t>>6))*2048 + (size_t)(t&63)*4;

    float e0[8], acc0[8], e1[8], acc1[8];
#pragma unroll
    for (int c = 0; c < 8; ++c){
        e0[c] = gu0[c] - uv0[c]; acc0[c] = 2.0f*uv0[c];
        e1[c] = gu1[c] - uv1[c]; acc1[c] = 2.0f*uv1[c];
    }
    matvec_acc(gmat, base0, e0, acc0);
    matvec_acc(gmat, base1, e1, acc1);
#pragma unroll
    for (int k = 0; k < 8; ++k){
        acc0[k] = gelu_f(acc0[k] + bias[k]);
        acc1[k] = gelu_f(acc1[k] + bias[k]);
    }
    store8(out + row0*2048 + (size_t)t*8, acc0);
    store8(out + (row0+1)*2048 + (size_t)t*8, acc1);
}

extern "C" void kernel_launch(void* const* d_in, const int* in_sizes, int n_in,
                              void* d_out, int out_size, void* d_ws, size_t ws_size,
                              hipStream_t stream) {
    const float* u_in = (const float*)d_in[0];
    const float* k_in = (const float*)d_in[1];
    const float* Wp[24];
    for (int i = 0; i < 24; ++i) Wp[i] = (const float*)d_in[2+i];
    const float* bias = (const float*)d_in[26];

    char* base = (char*)d_ws;
    unsigned* gmat  = (unsigned*)(base);                  // 32 MiB (bf16 pairs)
    unsigned* dmat  = (unsigned*)(base + 33554432ull);    // 32 MiB
    unsigned* fpack = (unsigned*)(base + 67108864ull);    // 8.45 MB (bf16 pairs)
    float*    u_ws  = (float*)   (base + 75563008ull);    // 8 MiB
    float2*   spec  = (float2*)  (base + 83951616ull);    // 8.45 MB -> ~92 MB

    prep_kernel<<<1153, 256, 0, stream>>>(k_in,
        Wp[0],Wp[1],Wp[2],Wp[3],Wp[4],Wp[5],
        Wp[6],Wp[7],Wp[8],Wp[9],Wp[10],Wp[11],
        Wp[12],Wp[13],Wp[14],Wp[15],Wp[16],Wp[17],
        Wp[18],Wp[19],Wp[20],Wp[21],Wp[22],Wp[23],
        gmat, dmat, fpack);

    fft_fwd_kernel<<<512, 256, 0, stream>>>(u_in, dmat, spec);
    for (int it = 0; it < 4; ++it){
        ffth_mult_kernel<<<516, 256, 0, stream>>>(spec, fpack);
        if (it < 3){
            born_step_kernel<<<512, 256, 0, stream>>>(
                spec, (it == 0) ? u_in : u_ws, u_ws, gmat, dmat);
        } else {
            final_kernel<<<512, 256, 0, stream>>>(spec, u_ws, gmat, bias, (float*)d_out);
        }
    }
}

// Round 15
// 210.353 us; speedup vs baseline: 1.0208x; 1.0208x over previous
//
#include <hip/hip_runtime.h>
#include <math.h>

// Problem constants
#define NB 4
#define HB 256
#define WB 256
#define CB 8
#define NPIX (NB*HB*WB)   // 262144
#define W2B 129           // rfft bins along W
#define TWO_PI_F 6.283185307179586f

typedef float f32x4 __attribute__((ext_vector_type(4)));

__device__ __forceinline__ float gelu_f(float x){
    float z = 0.7978845608028654f*(x + 0.044715f*x*x*x);
    return x * __builtin_amdgcn_rcpf(1.0f + __expf(-2.0f*z));
}

__device__ __forceinline__ unsigned pack_bf16x2(float a, float b){
    unsigned ua = __float_as_uint(a), ub = __float_as_uint(b);
    ua = (ua + 0x7FFFu + ((ua >> 16) & 1u)) >> 16;
    ub = (ub + 0x7FFFu + ((ub >> 16) & 1u)) >> 16;
    return ua | (ub << 16);
}
__device__ __forceinline__ float2 unpack_bf16x2(unsigned v){
    return make_float2(__uint_as_float(v << 16), __uint_as_float(v & 0xFFFF0000u));
}

__device__ __forceinline__ void ldcp(float* dst, const float* __restrict__ src, int n, int t){
    for (int i = t; i < n; i += 256) dst[i] = src[i];
}

// ---- prep (round-10/13 version) ----------------------------------------
// Grid: [0..128] spectral filter; [129..640] gamma 2px/thr; [641..1152] delta.
// mat layout (uint4 rows): mat[(pix>>6)*2048 + j*256 + (pix&63)*4 + c]
// fpack layout: fpack[w2*16384 + q*1024 + h*4 + c] = bf16x2{re,im}
__global__ __launch_bounds__(256) void prep_kernel(
    const float* __restrict__ kin,
    const float* gw1,const float* gb1,const float* gw2,const float* gb2,const float* gw3,const float* gb3,
    const float* dw1,const float* db1,const float* dw2,const float* db2,const float* dw3,const float* db3,
    const float* fw1,const float* fb1,const float* fw2,const float* fb2,const float* fw3,const float* fb3,
    const float* iw1,const float* ib1,const float* iw2,const float* ib2,const float* iw3,const float* ib3,
    unsigned* __restrict__ gmat, unsigned* __restrict__ dmat,
    unsigned* __restrict__ fpack)
{
    __shared__ __align__(16) float sw[2816];
    int t = threadIdx.x;
    int b = blockIdx.x;
    if (b >= 129){
        int gd = (b >= 641);
        const float* w1 = gd ? dw1 : gw1;  const float* b1 = gd ? db1 : gb1;
        const float* w2 = gd ? dw2 : gw2;  const float* b2 = gd ? db2 : gb2;
        const float* w3 = gd ? dw3 : gw3;  const float* b3 = gd ? db3 : gb3;
        ldcp(sw+0,   w1,  32, t); ldcp(sw+32,  b1, 16, t);
        ldcp(sw+48,  w2, 256, t); ldcp(sw+304, b2, 16, t);
        ldcp(sw+320, w3,1024, t); ldcp(sw+1344,b3, 64, t);
        __syncthreads();
        unsigned* mat = gd ? dmat : gmat;
        int p0 = (b - (gd ? 641 : 129))*512 + t;
        int p1 = p0 + 256;
        float2 kv0 = ((const float2*)kin)[p0];
        float2 kv1 = ((const float2*)kin)[p1];
        size_t base0 = (size_t)(p0 >> 6)*2048 + (size_t)(p0 & 63)*4;
        size_t base1 = (size_t)(p1 >> 6)*2048 + (size_t)(p1 & 63)*4;
        float h1[2][16], h2[2][16];
#pragma unroll
        for (int o = 0; o < 16; ++o){
            float wx = sw[o], wy = sw[16+o], bo = sw[32+o];
            h1[0][o] = gelu_f(kv0.x*wx + kv0.y*wy + bo);
            h1[1][o] = gelu_f(kv1.x*wx + kv1.y*wy + bo);
        }
#pragma unroll
        for (int oc = 0; oc < 4; ++oc){
            f32x4 bb = *(const f32x4*)(sw + 304 + oc*4);
            f32x4 a0 = bb, a1 = bb;
#pragma unroll
            for (int i = 0; i < 16; ++i){
                f32x4 w = *(const f32x4*)(sw + 48 + i*16 + oc*4);
                a0 += h1[0][i]*w; a1 += h1[1][i]*w;
            }
            h2[0][oc*4+0]=gelu_f(a0.x); h2[0][oc*4+1]=gelu_f(a0.y);
            h2[0][oc*4+2]=gelu_f(a0.z); h2[0][oc*4+3]=gelu_f(a0.w);
            h2[1][oc*4+0]=gelu_f(a1.x); h2[1][oc*4+1]=gelu_f(a1.y);
            h2[1][oc*4+2]=gelu_f(a1.z); h2[1][oc*4+3]=gelu_f(a1.w);
        }
        const float s = 1.0f/64.0f;
#pragma unroll
        for (int j = 0; j < 8; ++j){
            f32x4 bA = *(const f32x4*)(sw + 1344 + j*8);
            f32x4 bB = *(const f32x4*)(sw + 1344 + j*8 + 4);
            f32x4 A0 = bA, A1 = bB, B0 = bA, B1 = bB;
#pragma unroll
            for (int i = 0; i < 16; ++i){
                f32x4 wA = *(const f32x4*)(sw + 320 + i*64 + j*8);
                f32x4 wB = *(const f32x4*)(sw + 320 + i*64 + j*8 + 4);
                float h0 = h2[0][i], h1v = h2[1][i];
                A0 += h0*wA; A1 += h0*wB;
                B0 += h1v*wA; B1 += h1v*wB;
            }
            uint4 o0 = { pack_bf16x2(A0.x*s,A0.y*s), pack_bf16x2(A0.z*s,A0.w*s),
                         pack_bf16x2(A1.x*s,A1.y*s), pack_bf16x2(A1.z*s,A1.w*s) };
            uint4 o1 = { pack_bf16x2(B0.x*s,B0.y*s), pack_bf16x2(B0.z*s,B0.w*s),
                         pack_bf16x2(B1.x*s,B1.y*s), pack_bf16x2(B1.z*s,B1.w*s) };
            *(uint4*)(mat + base0 + (size_t)j*256) = o0;
            *(uint4*)(mat + base1 + (size_t)j*256) = o1;
        }
    } else {
        ldcp(sw+0,   fw1,  32, t); ldcp(sw+32,  fb1, 16, t);
        ldcp(sw+48,  fw2, 256, t); ldcp(sw+304, fb2, 16, t);
        ldcp(sw+320, fw3,1024, t); ldcp(sw+1344,fb3, 64, t);
        ldcp(sw+1408+0,   iw1,  32, t); ldcp(sw+1408+32,  ib1, 16, t);
        ldcp(sw+1408+48,  iw2, 256, t); ldcp(sw+1408+304, ib2, 16, t);
        ldcp(sw+1408+320, iw3,1024, t); ldcp(sw+1408+1344,ib3, 64, t);
        __syncthreads();
        int w2 = b;                                 // 0..128 (kx)
        float x = (float)w2;
        float y = (float)(t < 128 ? t : t - 256);   // ky signed, t = h-freq
        float h1r[16], h1i[16], h2r[16], h2i[16];
#pragma unroll
        for (int o = 0; o < 16; ++o){
            h1r[o] = gelu_f(x*sw[o] + y*sw[16+o] + sw[32+o]);
            h1i[o] = gelu_f(x*sw[1408+o] + y*sw[1408+16+o] + sw[1408+32+o]);
        }
#pragma unroll
        for (int o = 0; o < 16; ++o){
            float ar = sw[304+o], ai = sw[1408+304+o];
#pragma unroll
            for (int i = 0; i < 16; ++i){
                ar += h1r[i]*sw[48+i*16+o];
                ai += h1i[i]*sw[1408+48+i*16+o];
            }
            h2r[o] = gelu_f(ar); h2i[o] = gelu_f(ai);
        }
        const float s = 1.0f/64.0f;
#pragma unroll
        for (int q = 0; q < 16; ++q){
            f32x4 aR = *(const f32x4*)(sw + 1344 + q*4);
            f32x4 aI = *(const f32x4*)(sw + 1408 + 1344 + q*4);
#pragma unroll
            for (int i = 0; i < 16; ++i){
                aR += h2r[i] * *(const f32x4*)(sw + 320 + i*64 + q*4);
                aI += h2i[i] * *(const f32x4*)(sw + 1408 + 320 + i*64 + q*4);
            }
            uint4 out = { pack_bf16x2(aR.x*s, aI.x*s), pack_bf16x2(aR.y*s, aI.y*s),
                          pack_bf16x2(aR.z*s, aI.z*s), pack_bf16x2(aR.w*s, aI.w*s) };
            *(uint4*)(fpack + (size_t)w2*16384 + (size_t)q*1024 + (size_t)t*4) = out;
        }
    }
}

// ---- 256-pt complex FFT, 4 interleaved channels (f32x4 LDS) ------------
__device__ __forceinline__ void fft256v(f32x4* xr, f32x4* xi, int t, float sgn)
{
    int n2 = t >> 4, k1 = t & 15;
    float csA, snA; __sincosf(sgn*TWO_PI_F*(float)k1*(1.0f/16.0f), &snA, &csA);
    f32x4 ar = {0.f,0.f,0.f,0.f}, ai = {0.f,0.f,0.f,0.f};
    float cw = 1.f, sw = 0.f;
#pragma unroll
    for (int n1 = 0; n1 < 16; ++n1){
        f32x4 vr = xr[16*n1 + n2], vi = xi[16*n1 + n2];
        ar += vr*cw - vi*sw;
        ai += vr*sw + vi*cw;
        float cn = cw*csA - sw*snA;
        sw = cw*snA + sw*csA; cw = cn;
    }
    float cs2, sn2; __sincosf(sgn*TWO_PI_F*(float)(n2*k1)*(1.0f/256.0f), &sn2, &cs2);
    f32x4 br = ar*cs2 - ai*sn2;
    f32x4 bi = ar*sn2 + ai*cs2;
    __syncthreads();
    xr[t] = br; xi[t] = bi;
    __syncthreads();
    int k1b = t & 15, k2 = t >> 4;
    float csB, snB; __sincosf(sgn*TWO_PI_F*(float)k2*(1.0f/16.0f), &snB, &csB);
    f32x4 yr = {0.f,0.f,0.f,0.f}, yi = {0.f,0.f,0.f,0.f};
    cw = 1.f; sw = 0.f;
#pragma unroll
    for (int n2b = 0; n2b < 16; ++n2b){
        f32x4 br2 = xr[n2b*16 + k1b], bi2 = xi[n2b*16 + k1b];
        yr += br2*cw - bi2*sw;
        yi += br2*sw + bi2*cw;
        float cn = cw*csB - sw*snB;
        sw = cw*snB + sw*csB; cw = cn;
    }
    __syncthreads();
    xr[t] = yr; xi[t] = yi;
    __syncthreads();
}

// Core version: result returned in registers; no final store/sync.
__device__ __forceinline__ void fft256v_core(f32x4* xr, f32x4* xi, int t, float sgn,
                                             f32x4& outR, f32x4& outI)
{
    int n2 = t >> 4, k1 = t & 15;
    float csA, snA; __sincosf(sgn*TWO_PI_F*(float)k1*(1.0f/16.0f), &snA, &csA);
    f32x4 ar = {0.f,0.f,0.f,0.f}, ai = {0.f,0.f,0.f,0.f};
    float cw = 1.f, sw = 0.f;
#pragma unroll
    for (int n1 = 0; n1 < 16; ++n1){
        f32x4 vr = xr[16*n1 + n2], vi = xi[16*n1 + n2];
        ar += vr*cw - vi*sw;
        ai += vr*sw + vi*cw;
        float cn = cw*csA - sw*snA;
        sw = cw*snA + sw*csA; cw = cn;
    }
    float cs2, sn2; __sincosf(sgn*TWO_PI_F*(float)(n2*k1)*(1.0f/256.0f), &sn2, &cs2);
    f32x4 br = ar*cs2 - ai*sn2;
    f32x4 bi = ar*sn2 + ai*cs2;
    __syncthreads();
    xr[t] = br; xi[t] = bi;
    __syncthreads();
    int k1b = t & 15, k2 = t >> 4;
    float csB, snB; __sincosf(sgn*TWO_PI_F*(float)k2*(1.0f/16.0f), &snB, &csB);
    f32x4 yr = {0.f,0.f,0.f,0.f}, yi = {0.f,0.f,0.f,0.f};
    cw = 1.f; sw = 0.f;
#pragma unroll
    for (int n2b = 0; n2b < 16; ++n2b){
        f32x4 br2 = xr[n2b*16 + k1b], bi2 = xi[n2b*16 + k1b];
        yr += br2*cw - bi2*sw;
        yi += br2*sw + bi2*cw;
        float cn = cw*csB - sw*snB;
        sw = cw*snB + sw*csB; cw = cn;
    }
    outR = yr; outI = yi;
}

// 8-channel core: two f32x4 halves batched through one barrier set.
__device__ __forceinline__ void fft256v8_core(
    f32x4 (*xr)[256], f32x4 (*xi)[256], int t, float sgn,
    f32x4& o0R, f32x4& o0I, f32x4& o1R, f32x4& o1I)
{
    int n2 = t >> 4, k1 = t & 15;
    float csA, snA; __sincosf(sgn*TWO_PI_F*(float)k1*(1.0f/16.0f), &snA, &csA);
    f32x4 a0r={0.f,0.f,0.f,0.f}, a0i=a0r, a1r=a0r, a1i=a0r;
    float cw = 1.f, sw = 0.f;
#pragma unroll
    for (int n1 = 0; n1 < 16; ++n1){
        int idx = 16*n1 + n2;
        f32x4 v0r = xr[0][idx], v0i = xi[0][idx];
        f32x4 v1r = xr[1][idx], v1i = xi[1][idx];
        a0r += v0r*cw - v0i*sw;  a0i += v0r*sw + v0i*cw;
        a1r += v1r*cw - v1i*sw;  a1i += v1r*sw + v1i*cw;
        float cn = cw*csA - sw*snA;
        sw = cw*snA + sw*csA; cw = cn;
    }
    float cs2, sn2; __sincosf(sgn*TWO_PI_F*(float)(n2*k1)*(1.0f/256.0f), &sn2, &cs2);
    f32x4 b0r = a0r*cs2 - a0i*sn2, b0i = a0r*sn2 + a0i*cs2;
    f32x4 b1r = a1r*cs2 - a1i*sn2, b1i = a1r*sn2 + a1i*cs2;
    __syncthreads();
    xr[0][t]=b0r; xi[0][t]=b0i; xr[1][t]=b1r; xi[1][t]=b1i;
    __syncthreads();
    int k1b = t & 15, k2 = t >> 4;
    float csB, snB; __sincosf(sgn*TWO_PI_F*(float)k2*(1.0f/16.0f), &snB, &csB);
    f32x4 y0r={0.f,0.f,0.f,0.f}, y0i=y0r, y1r=y0r, y1i=y0r;
    cw = 1.f; sw = 0.f;
#pragma unroll
    for (int n2b = 0; n2b < 16; ++n2b){
        int idx = n2b*16 + k1b;
        f32x4 c0r = xr[0][idx], c0i = xi[0][idx];
        f32x4 c1r = xr[1][idx], c1i = xi[1][idx];
        y0r += c0r*cw - c0i*sw;  y0i += c0r*sw + c0i*cw;
        y1r += c1r*cw - c1i*sw;  y1i += c1r*sw + c1i*cw;
        float cn = cw*csB - sw*snB;
        sw = cw*snB + sw*csB; cw = cn;
    }
    o0R = y0r; o0I = y0i; o1R = y1r; o1I = y1i;
}

// du row -> fwd FFT -> Hermitian split -> spec write (t<=128)
__device__ __forceinline__ void fwd_store(
    f32x4* XR, f32x4* XI, const float* dv, int t, int n, int h,
    float2* __restrict__ spec)
{
    XR[t] = (f32x4){dv[0],dv[2],dv[4],dv[6]};
    XI[t] = (f32x4){dv[1],dv[3],dv[5],dv[7]};
    __syncthreads();
    fft256v(XR, XI, t, -1.f);
    if (t <= 128){
        int m = (256 - t) & 255;
        f32x4 zr = XR[t], zi = XI[t], yr = XR[m], yi = XI[m];
        float4* dst = (float4*)(spec + (((size_t)n*129 + t)*256 + h)*8);
        dst[0] = make_float4(0.5f*(zr.x+yr.x), 0.5f*(zi.x-yi.x), 0.5f*(zi.x+yi.x), 0.5f*(yr.x-zr.x));
        dst[1] = make_float4(0.5f*(zr.y+yr.y), 0.5f*(zi.y-yi.y), 0.5f*(zi.y+yi.y), 0.5f*(yr.y-zr.y));
        dst[2] = make_float4(0.5f*(zr.z+yr.z), 0.5f*(zi.z-yi.z), 0.5f*(zi.z+yi.z), 0.5f*(yr.z-zr.z));
        dst[3] = make_float4(0.5f*(zr.w+yr.w), 0.5f*(zi.w-yi.w), 0.5f*(zi.w+yi.w), 0.5f*(yr.w-zr.w));
    }
}

// direct Hermitian read -> inv FFT (core) -> gu[8] in registers.
__device__ __forceinline__ void inv_fft_to_gu(
    const float2* __restrict__ spec, f32x4* XR, f32x4* XI,
    int t, int n, int h, float* gu)
{
    int w2 = (t <= 128) ? t : 256 - t;
    const float4* rp = (const float4*)(spec + (((size_t)n*129 + w2)*256 + h)*8);
    float4 q0 = rp[0], q1 = rp[1], q2 = rp[2], q3 = rp[3];
    f32x4 xr, xi;
    if (t <= 128){
        xr = (f32x4){q0.x - q0.w, q1.x - q1.w, q2.x - q2.w, q3.x - q3.w};
        xi = (f32x4){q0.y + q0.z, q1.y + q1.z, q2.y + q2.z, q3.y + q3.z};
    } else {
        xr = (f32x4){ q0.x + q0.w,  q1.x + q1.w,  q2.x + q2.w,  q3.x + q3.w};
        xi = (f32x4){-q0.y + q0.z, -q1.y + q1.z, -q2.y + q2.z, -q3.y + q3.z};
    }
    XR[t] = xr; XI[t] = xi;
    __syncthreads();
    f32x4 gr, gi;
    fft256v_core(XR, XI, t, +1.f, gr, gi);
    const float s = 1.0f/65536.0f;
    gu[0]=gr.x*s; gu[1]=gi.x*s; gu[2]=gr.y*s; gu[3]=gi.y*s;
    gu[4]=gr.z*s; gu[5]=gi.z*s; gu[6]=gr.w*s; gu[7]=gi.w*s;
}

// matvec accumulate: acc[k] += v[j] * M[j][k], M in uint4-row layout
__device__ __forceinline__ void matvec_acc(const unsigned* __restrict__ mat,
                                           size_t base, const float* v, float* acc)
{
    const uint4* mp = (const uint4*)(mat + base);
#pragma unroll
    for (int j = 0; j < 8; ++j){
        uint4 q = mp[j*64];
        float vj = v[j];
        float2 f0 = unpack_bf16x2(q.x), f1 = unpack_bf16x2(q.y);
        float2 f2 = unpack_bf16x2(q.z), f3 = unpack_bf16x2(q.w);
        acc[0] += vj*f0.x; acc[1] += vj*f0.y;
        acc[2] += vj*f1.x; acc[3] += vj*f1.y;
        acc[4] += vj*f2.x; acc[5] += vj*f2.y;
        acc[6] += vj*f3.x; acc[7] += vj*f3.y;
    }
}

// ---- initial: du = u*Delta, forward rfft along W -----------------------
__global__ __launch_bounds__(256) void fft_fwd_kernel(
    const float* __restrict__ u, const unsigned* __restrict__ dmat,
    float2* __restrict__ spec)
{
    __shared__ f32x4 XR[256], XI[256];
    int t = threadIdx.x, bid = blockIdx.x;
    int n = bid >> 8, h = bid & 255;
    const float* up = u + (size_t)bid*2048 + (size_t)t*8;
    float4 ua = ((const float4*)up)[0], ub = ((const float4*)up)[1];
    float uv[8] = {ua.x,ua.y,ua.z,ua.w, ub.x,ub.y,ub.z,ub.w};
    size_t base = (size_t)(bid*4 + (t>>6))*2048 + (size_t)(t&63)*4;
    float dv[8] = {0,0,0,0,0,0,0,0};
    matvec_acc(dmat, base, uv, dv);
    fwd_store(XR, XI, dv, t, n, h, spec);
}

// ---- fused: cfft along H -> per-frequency 8x8 complex mat -> icfft -----
// 256 threads, 8 channels/thread. Block remap: w2 = bid>>2, n = bid&3 so
// the 4 blocks sharing a fpack slice dispatch adjacently (L2 locality).
__global__ __launch_bounds__(256) void ffth_mult_kernel(
    float2* __restrict__ spec, const unsigned* __restrict__ fpack)
{
    __shared__ f32x4 XR[2][256], XI[2][256];
    int t = threadIdx.x;
    int w2 = blockIdx.x >> 2, n = blockIdx.x & 3;
    float2* base = spec + ((size_t)(n*129 + w2))*2048;
    const float4* rp = (const float4*)(base + (size_t)t*8);
    float4 r0 = rp[0], r1 = rp[1], r2 = rp[2], r3 = rp[3];
    XR[0][t] = (f32x4){r0.x, r0.z, r1.x, r1.z};
    XI[0][t] = (f32x4){r0.y, r0.w, r1.y, r1.w};
    XR[1][t] = (f32x4){r2.x, r2.z, r3.x, r3.z};
    XI[1][t] = (f32x4){r2.y, r2.w, r3.y, r3.w};
    __syncthreads();
    f32x4 s0R, s0I, s1R, s1I;
    fft256v8_core(XR, XI, t, -1.f, s0R, s0I, s1R, s1I);

    float sr[8] = {s0R.x,s0R.y,s0R.z,s0R.w, s1R.x,s1R.y,s1R.z,s1R.w};
    float si[8] = {s0I.x,s0I.y,s0I.z,s0I.w, s1I.x,s1I.y,s1I.z,s1I.w};
    f32x4 o0R={0.f,0.f,0.f,0.f}, o0I=o0R, o1R=o0R, o1I=o0R;
    const uint4* fp = (const uint4*)(fpack + (size_t)w2*16384 + (size_t)t*4);
#pragma unroll
    for (int j = 0; j < 8; ++j){
        float sjr = sr[j], sji = si[j];
        uint4 fa = fp[(j*2+0)*256];       // out k 0..3
        uint4 fb = fp[(j*2+1)*256];       // out k 4..7
        float2 f0 = unpack_bf16x2(fa.x), f1 = unpack_bf16x2(fa.y);
        float2 f2 = unpack_bf16x2(fa.z), f3 = unpack_bf16x2(fa.w);
        o0R.x += sjr*f0.x - sji*f0.y;  o0I.x += sjr*f0.y + sji*f0.x;
        o0R.y += sjr*f1.x - sji*f1.y;  o0I.y += sjr*f1.y + sji*f1.x;
        o0R.z += sjr*f2.x - sji*f2.y;  o0I.z += sjr*f2.y + sji*f2.x;
        o0R.w += sjr*f3.x - sji*f3.y;  o0I.w += sjr*f3.y + sji*f3.x;
        float2 g0 = unpack_bf16x2(fb.x), g1 = unpack_bf16x2(fb.y);
        float2 g2 = unpack_bf16x2(fb.z), g3 = unpack_bf16x2(fb.w);
        o1R.x += sjr*g0.x - sji*g0.y;  o1I.x += sjr*g0.y + sji*g0.x;
        o1R.y += sjr*g1.x - sji*g1.y;  o1I.y += sjr*g1.y + sji*g1.x;
        o1R.z += sjr*g2.x - sji*g2.y;  o1I.z += sjr*g2.y + sji*g2.x;
        o1R.w += sjr*g3.x - sji*g3.y;  o1I.w += sjr*g3.y + sji*g3.x;
    }
    __syncthreads();    // fwd stage-2 LDS reads complete
    XR[0][t]=o0R; XI[0][t]=o0I; XR[1][t]=o1R; XI[1][t]=o1I;
    __syncthreads();
    f32x4 v0R, v0I, v1R, v1I;
    fft256v8_core(XR, XI, t, +1.f, v0R, v0I, v1R, v1I);
    float4* wp = (float4*)(base + (size_t)t*8);
    wp[0] = make_float4(v0R.x, v0I.x, v0R.y, v0I.y);
    wp[1] = make_float4(v0R.z, v0I.z, v0R.w, v0I.w);
    wp[2] = make_float4(v1R.x, v1I.x, v1R.y, v1I.y);
    wp[3] = make_float4(v1R.z, v1I.z, v1R.w, v1I.w);
}

// ---- fused step: inv-W-FFT -> u' = 2u+(gu-u)G -> du = u'D -> fwd-W-FFT -
__global__ __launch_bounds__(256) void born_step_kernel(
    float2* __restrict__ spec, const float* __restrict__ u_in,
    float* __restrict__ u_out, const unsigned* __restrict__ gmat,
    const unsigned* __restrict__ dmat)
{
    __shared__ f32x4 XR[256], XI[256];
    int t = threadIdx.x, bid = blockIdx.x;
    int n = bid >> 8, h = bid & 255;
    float gu[8];
    inv_fft_to_gu(spec, XR, XI, t, n, h, gu);

    const float* up = u_in + (size_t)bid*2048 + (size_t)t*8;
    float4 ua = ((const float4*)up)[0], ub = ((const float4*)up)[1];
    float uv[8] = {ua.x,ua.y,ua.z,ua.w, ub.x,ub.y,ub.z,ub.w};
    float e[8], acc[8];
#pragma unroll
    for (int c = 0; c < 8; ++c){ e[c] = gu[c] - uv[c]; acc[c] = 2.0f*uv[c]; }
    size_t base = (size_t)(bid*4 + (t>>6))*2048 + (size_t)(t&63)*4;
    matvec_acc(gmat, base, e, acc);
    float* op = u_out + (size_t)bid*2048 + (size_t)t*8;
    ((float4*)op)[0] = make_float4(acc[0],acc[1],acc[2],acc[3]);
    ((float4*)op)[1] = make_float4(acc[4],acc[5],acc[6],acc[7]);

    float dv[8] = {0,0,0,0,0,0,0,0};
    matvec_acc(dmat, base, acc, dv);
    __syncthreads();   // guard: laggards may still read XR/XI from inv stage-2
    fwd_store(XR, XI, dv, t, n, h, spec);
}

// ---- final: inv-W-FFT -> u' -> gelu(u'+bias) -> out --------------------
__global__ __launch_bounds__(256) void final_kernel(
    const float2* __restrict__ spec, const float* __restrict__ u_in,
    const unsigned* __restrict__ gmat, const float* __restrict__ bias,
    float* __restrict__ out)
{
    __shared__ f32x4 XR[256], XI[256];
    int t = threadIdx.x, bid = blockIdx.x;
    int n = bid >> 8, h = bid & 255;
    float gu[8];
    inv_fft_to_gu(spec, XR, XI, t, n, h, gu);

    const float* up = u_in + (size_t)bid*2048 + (size_t)t*8;
    float4 ua = ((const float4*)up)[0], ub = ((const float4*)up)[1];
    float uv[8] = {ua.x,ua.y,ua.z,ua.w, ub.x,ub.y,ub.z,ub.w};
    float e[8], acc[8];
#pragma unroll
    for (int c = 0; c < 8; ++c){ e[c] = gu[c] - uv[c]; acc[c] = 2.0f*uv[c]; }
    size_t base = (size_t)(bid*4 + (t>>6))*2048 + (size_t)(t&63)*4;
    matvec_acc(gmat, base, e, acc);
#pragma unroll
    for (int k = 0; k < 8; ++k) acc[k] = gelu_f(acc[k] + bias[k]);
    float* op = out + (size_t)bid*2048 + (size_t)t*8;
    ((float4*)op)[0] = make_float4(acc[0],acc[1],acc[2],acc[3]);
    ((float4*)op)[1] = make_float4(acc[4],acc[5],acc[6],acc[7]);
}

extern "C" void kernel_launch(void* const* d_in, const int* in_sizes, int n_in,
                              void* d_out, int out_size, void* d_ws, size_t ws_size,
                              hipStream_t stream) {
    const float* u_in = (const float*)d_in[0];
    const float* k_in = (const float*)d_in[1];
    const float* Wp[24];
    for (int i = 0; i < 24; ++i) Wp[i] = (const float*)d_in[2+i];
    const float* bias = (const float*)d_in[26];

    char* base = (char*)d_ws;
    unsigned* gmat  = (unsigned*)(base);                  // 32 MiB (bf16 pairs)
    unsigned* dmat  = (unsigned*)(base + 33554432ull);    // 32 MiB
    unsigned* fpack = (unsigned*)(base + 67108864ull);    // 8.45 MB (bf16 pairs)
    float*    u_ws  = (float*)   (base + 75563008ull);    // 8 MiB
    float2*   spec  = (float2*)  (base + 83951616ull);    // 8.45 MB -> ~92 MB

    prep_kernel<<<1153, 256, 0, stream>>>(k_in,
        Wp[0],Wp[1],Wp[2],Wp[3],Wp[4],Wp[5],
        Wp[6],Wp[7],Wp[8],Wp[9],Wp[10],Wp[11],
        Wp[12],Wp[13],Wp[14],Wp[15],Wp[16],Wp[17],
        Wp[18],Wp[19],Wp[20],Wp[21],Wp[22],Wp[23],
        gmat, dmat, fpack);

    fft_fwd_kernel<<<1024, 256, 0, stream>>>(u_in, dmat, spec);
    for (int it = 0; it < 4; ++it){
        ffth_mult_kernel<<<516, 256, 0, stream>>>(spec, fpack);
        if (it < 3){
            born_step_kernel<<<1024, 256, 0, stream>>>(
                spec, (it == 0) ? u_in : u_ws, u_ws, gmat, dmat);
        } else {
            final_kernel<<<1024, 256, 0, stream>>>(spec, u_ws, gmat, bias, (float*)d_out);
        }
    }
}